// Round 21
// baseline (59.876 us; speedup 1.0000x reference)
//
#include <hip/hip_runtime.h>

#define NB 8

typedef float f2 __attribute__((ext_vector_type(2)));

// Fused: gray (levels 0,1) + pyramid levels 2,3 via block-local LDS reduction.
__global__ __launch_bounds__(256) void gray_pyr_kernel(
    const float* __restrict__ img1, const float* __restrict__ img2,
    float* __restrict__ g0a, float* __restrict__ g0b,
    float* __restrict__ g1a, float* __restrict__ g1b,
    float* __restrict__ g2a, float* __restrict__ g2b,
    float* __restrict__ g3a, float* __restrict__ g3b) {
    const int W = 512, HW = 512 * 512;
    __shared__ float sL1a[16][17], sL1b[16][17];
    __shared__ float sL2a[8][9], sL2b[8][9];

    int blk = blockIdx.x;
    int b = blk % NB;
    int t = blk / NB;              // 0..255
    int ty = t / 16, tx = t % 16;  // level-1 tile coords
    int lx = threadIdx.x % 16, ly = threadIdx.x / 16;
    int y1 = ty * 16 + ly, x1 = tx * 16 + lx;

    size_t base = (size_t)b * 3 * HW + (size_t)(2 * y1) * W + 2 * x1;
    const float third = 1.0f / 3.0f;

    f2 a0c0 = __builtin_nontemporal_load((const f2*)(img1 + base));
    f2 a1c0 = __builtin_nontemporal_load((const f2*)(img1 + base + W));
    f2 a0c1 = __builtin_nontemporal_load((const f2*)(img1 + base + HW));
    f2 a1c1 = __builtin_nontemporal_load((const f2*)(img1 + base + HW + W));
    f2 a0c2 = __builtin_nontemporal_load((const f2*)(img1 + base + 2 * HW));
    f2 a1c2 = __builtin_nontemporal_load((const f2*)(img1 + base + 2 * HW + W));
    float p00 = (a0c0.x + a0c1.x + a0c2.x) * third;
    float p01 = (a0c0.y + a0c1.y + a0c2.y) * third;
    float p10 = (a1c0.x + a1c1.x + a1c2.x) * third;
    float p11 = (a1c0.y + a1c1.y + a1c2.y) * third;
    size_t gbase = (size_t)b * HW + (size_t)(2 * y1) * W + 2 * x1;
    *(f2*)(g0a + gbase) = (f2){p00, p01};
    *(f2*)(g0a + gbase + W) = (f2){p10, p11};
    float pa = (p00 + p01 + p10 + p11) * 0.25f;
    g1a[(size_t)b * 256 * 256 + y1 * 256 + x1] = pa;
    sL1a[ly][lx] = pa;

    f2 b0c0 = __builtin_nontemporal_load((const f2*)(img2 + base));
    f2 b1c0 = __builtin_nontemporal_load((const f2*)(img2 + base + W));
    f2 b0c1 = __builtin_nontemporal_load((const f2*)(img2 + base + HW));
    f2 b1c1 = __builtin_nontemporal_load((const f2*)(img2 + base + HW + W));
    f2 b0c2 = __builtin_nontemporal_load((const f2*)(img2 + base + 2 * HW));
    f2 b1c2 = __builtin_nontemporal_load((const f2*)(img2 + base + 2 * HW + W));
    float q00 = (b0c0.x + b0c1.x + b0c2.x) * third;
    float q01 = (b0c0.y + b0c1.y + b0c2.y) * third;
    float q10 = (b1c0.x + b1c1.x + b1c2.x) * third;
    float q11 = (b1c0.y + b1c1.y + b1c2.y) * third;
    *(f2*)(g0b + gbase) = (f2){q00, q01};
    *(f2*)(g0b + gbase + W) = (f2){q10, q11};
    float pb = (q00 + q01 + q10 + q11) * 0.25f;
    g1b[(size_t)b * 256 * 256 + y1 * 256 + x1] = pb;
    sL1b[ly][lx] = pb;
    __syncthreads();

    if (threadIdx.x < 64) {
        int y2 = threadIdx.x / 8, x2 = threadIdx.x % 8;
        float va = (sL1a[2 * y2][2 * x2] + sL1a[2 * y2][2 * x2 + 1]
                  + sL1a[2 * y2 + 1][2 * x2] + sL1a[2 * y2 + 1][2 * x2 + 1]) * 0.25f;
        float vb = (sL1b[2 * y2][2 * x2] + sL1b[2 * y2][2 * x2 + 1]
                  + sL1b[2 * y2 + 1][2 * x2] + sL1b[2 * y2 + 1][2 * x2 + 1]) * 0.25f;
        g2a[(size_t)b * 128 * 128 + (ty * 8 + y2) * 128 + tx * 8 + x2] = va;
        g2b[(size_t)b * 128 * 128 + (ty * 8 + y2) * 128 + tx * 8 + x2] = vb;
        sL2a[y2][x2] = va;
        sL2b[y2][x2] = vb;
    }
    __syncthreads();

    if (threadIdx.x < 16) {
        int y3 = threadIdx.x / 4, x3 = threadIdx.x % 4;
        float va = (sL2a[2 * y3][2 * x3] + sL2a[2 * y3][2 * x3 + 1]
                  + sL2a[2 * y3 + 1][2 * x3] + sL2a[2 * y3 + 1][2 * x3 + 1]) * 0.25f;
        float vb = (sL2b[2 * y3][2 * x3] + sL2b[2 * y3][2 * x3 + 1]
                  + sL2b[2 * y3 + 1][2 * x3] + sL2b[2 * y3 + 1][2 * x3 + 1]) * 0.25f;
        g3a[(size_t)b * 64 * 64 + (ty * 4 + y3) * 64 + tx * 4 + x3] = va;
        g3b[(size_t)b * 64 * 64 + (ty * 4 + y3) * 64 + tx * 4 + x3] = vb;
    }
}

// Phase-split rolling strip. MODE=1 warp gather: coalesced G2 row window +
// per-lane shuffle bilinear with dyi in {-1,0} (6 shuffles + 4 selects/row);
// per-lane exec-masked pair-load fallback for edge/outlier lanes (r19 path).
template <int MODE, int H, int W, int TH>
__device__ __forceinline__ void lk_strip(
    int b, int tix, const float* __restrict__ g1, const float* __restrict__ g2,
    const float* __restrict__ fin, float* __restrict__ fout) {
    constexpr int XT = (W + 57) / 58;
    constexpr int NR = TH + 4;
    constexpr int Hs = H / 2, Ws = W / 2;
    constexpr float scale = (float)(Hs - 1) / (float)(H - 1);

    const int lane = threadIdx.x & 63;
    const int xt = tix % XT, yt = tix / XT;
    const int xb = xt * 58 - 3;
    const int x = xb + lane;
    const bool xin = (x >= 0) && (x < W);

    const float* G1 = g1 + (size_t)b * H * W;
    const float* G2 = g2 + (size_t)b * H * W;
    float* FO = fout + (size_t)b * 2 * H * W;

    const int p0 = yt * TH - 2;

    auto issue1 = [&](int yy) -> float {
        return (xin && yy >= 0 && yy < H) ? G1[yy * W + x] : 0.0f;
    };
    auto dands = [&](float gv, float& d, float& s) {
        float gl = __shfl_up(gv, 1);
        float gr = __shfl_down(gv, 1);
        d = gr - gl;
        s = gl + 2.0f * gv + gr;
    };
    auto hs5 = [&](float v) {
        float a = __shfl_down(v, 1);
        float c = __shfl_down(v, 2);
        float t = v + a + c;
        return __shfl_up(t, 2) + a + c;
    };

    // phase 0: G1 rows (+ G2 row window w[j] = G2row(p0-1+j), coalesced/clamped)
    float g[NR + 2];
#pragma unroll
    for (int j = 0; j < NR + 2; ++j) g[j] = issue1(p0 - 1 + j);

    float w[MODE ? NR + 3 : 1];
    if (MODE) {
        int xc = min(max(x, 0), W - 1);
#pragma unroll
        for (int j = 0; j < NR + 3; ++j) {
            int row = min(max(p0 - 1 + j, 0), H - 1);
            w[j] = G2[row * W + xc];
        }
    }

    float i2w[NR];
    if (!MODE) {
#pragma unroll
        for (int i = 0; i < NR; ++i) {
            int yc = p0 + i;
            i2w[i] = (xin && yc >= 0 && yc < H) ? G2[yc * W + x] : 0.0f;
        }
    }

    // phase 1: flow walk + warp sample -> i2w
    float su[MODE ? NR : 1], sv[MODE ? NR : 1];
    if (MODE) {
        const float* FU = fin + (size_t)b * 2 * Hs * Ws;
        const float* FV = FU + Hs * Ws;
        float sx = (float)x * scale;
        int cx0 = min(max((int)sx, 0), Ws - 2);
        float wxf = sx - (float)cx0;
        int y0cur = min(max((int)((float)p0 * scale), 0), Hs - 2);
        f2 cu0, cu1, cv0, cv1;
        __builtin_memcpy(&cu0, FU + y0cur * Ws + cx0, 8);
        __builtin_memcpy(&cu1, FU + (y0cur + 1) * Ws + cx0, 8);
        __builtin_memcpy(&cv0, FV + y0cur * Ws + cx0, 8);
        __builtin_memcpy(&cv1, FV + (y0cur + 1) * Ws + cx0, 8);
        // wave-uniform valid lane-column span of the row window
        const int lo = (xb < 0) ? -xb : 0;
        const int hi = (W - 1 - xb < 63) ? (W - 1 - xb) : 63;
#pragma unroll
        for (int i = 0; i < NR; ++i) {
            int yc = p0 + i;
            int y0i = min(max((int)((float)yc * scale), 0), Hs - 2);
            if (y0i != y0cur) {  // wave-uniform advance
                cu0 = cu1; cv0 = cv1;
                __builtin_memcpy(&cu1, FU + (y0i + 1) * Ws + cx0, 8);
                __builtin_memcpy(&cv1, FV + (y0i + 1) * Ws + cx0, 8);
                y0cur = y0i;
            }
            float wyf = (float)yc * scale - (float)y0cur;
            float ut = cu0.x + (cu1.x - cu0.x) * wyf;
            float ub = cu0.y + (cu1.y - cu0.y) * wyf;
            float vt = cv0.x + (cv1.x - cv0.x) * wyf;
            float vb = cv0.y + (cv1.y - cv0.y) * wyf;
            su[i] = 2.0f * (ut + (ub - ut) * wxf);
            sv[i] = 2.0f * (vt + (vb - vt) * wxf);

            float xx = (float)x + su[i], yy2 = (float)yc + sv[i];
            float x0f = floorf(xx), y0f = floorf(yy2);
            float wx = xx - x0f, wy = yy2 - y0f;
            int xi = (int)x0f, yi = (int)y0f;
            int dyi = yi - yc;          // in {-1,0} for |sv|<1
            int li = xi - xb;
            bool ok = (li >= lo) && (li + 1 <= hi)
                   && (dyi >= -1) && (dyi <= 0)
                   && (yi >= 0) && (yi + 1 <= H - 1);
            // 6 shuffles from candidate rows w[i](yc-1), w[i+1](yc), w[i+2](yc+1)
            int lc = min(max(li, 0), 62);
            float s0a = __shfl(w[i], lc);
            float s0b = __shfl(w[i], lc + 1);
            float s1a = __shfl(w[i + 1], lc);
            float s1b = __shfl(w[i + 1], lc + 1);
            float s2a = __shfl(w[i + 2], lc);
            float s2b = __shfl(w[i + 2], lc + 1);
            bool dm1 = (dyi == -1);
            float v00 = dm1 ? s0a : s1a;
            float v01 = dm1 ? s0b : s1b;
            float v10 = dm1 ? s1a : s2a;
            float v11 = dm1 ? s1b : s2b;
            float fast = v00 * ((1.0f - wx) * (1.0f - wy))
                       + v01 * (wx * (1.0f - wy))
                       + v10 * ((1.0f - wx) * wy)
                       + v11 * (wx * wy);
            if (ok) {
                i2w[i] = fast;
            } else {
                // fallback: r19 pair-load + mask path (bit-exact reference)
                int xl = min(max(xi, 0), W - 2);
                int ya = min(max(yi, 0), H - 1), yb2 = min(max(yi + 1, 0), H - 1);
                f2 wtv, wbv;
                __builtin_memcpy(&wtv, G2 + ya * W + xl, 8);
                __builtin_memcpy(&wbv, G2 + yb2 * W + xl, 8);
                bool t0 = (xi == xl);
                float e00 = t0 ? wtv.x : wtv.y;
                float e01 = t0 ? wtv.y : wtv.x;
                float e10 = t0 ? wbv.x : wbv.y;
                float e11 = t0 ? wbv.y : wbv.x;
                float mx0 = (xi >= 0 && xi < W) ? 1.0f : 0.0f;
                float mx1 = (xi >= -1 && xi < W - 1) ? 1.0f : 0.0f;
                float my0 = (yi >= 0 && yi < H) ? 1.0f : 0.0f;
                float my1 = (yi >= -1 && yi < H - 1) ? 1.0f : 0.0f;
                i2w[i] = e00 * ((1.0f - wx) * (1.0f - wy) * mx0 * my0)
                       + e01 * (wx * (1.0f - wy) * mx1 * my0)
                       + e10 * ((1.0f - wx) * wy * mx0 * my1)
                       + e11 * (wx * wy * mx1 * my1);
            }
        }
    }

    // phase 2: consume
    float hxx[5], hyy[5], hxy[5], hxt[5], hyt[5];
#pragma unroll
    for (int k = 0; k < 5; ++k) { hxx[k] = hyy[k] = hxy[k] = hxt[k] = hyt[k] = 0.0f; }

    float dm, d0, sm, s0, dp, sp;
    dands(g[0], dm, sm);
    dands(g[1], d0, s0);

#pragma unroll
    for (int i = 0; i < NR; ++i) {
        const int yc = p0 + i;
        dands(g[i + 2], dp, sp);
        float Ix = (dm + 2.0f * d0 + dp) * 0.125f;
        float Iy = (sp - sm) * 0.125f;
        float It = i2w[i] - g[i + 1];
        float vm = (xin && yc >= 0 && yc < H) ? 1.0f : 0.0f;
        Ix *= vm; Iy *= vm; It *= vm;

        const int k = i % 5;  // static after full unroll
        hxx[k] = Ix * Ix;
        hyy[k] = Iy * Iy;
        hxy[k] = Ix * Iy;
        hxt[k] = Ix * It;
        hyt[k] = Iy * It;

        if (i >= 4) {
            float vxx = hxx[0] + hxx[1] + hxx[2] + hxx[3] + hxx[4];
            float vyy = hyy[0] + hyy[1] + hyy[2] + hyy[3] + hyy[4];
            float vxy = hxy[0] + hxy[1] + hxy[2] + hxy[3] + hxy[4];
            float vxt = hxt[0] + hxt[1] + hxt[2] + hxt[3] + hxt[4];
            float vyt = hyt[0] + hyt[1] + hyt[2] + hyt[3] + hyt[4];
            float Sxx = hs5(vxx);
            float Syy = hs5(vyy);
            float Sxy = hs5(vxy);
            float Sxt = hs5(vxt);
            float Syt = hs5(vyt);
            float inv = 1.0f / (Sxx * Syy - Sxy * Sxy + 1e-6f);
            float du = (-Syy * Sxt + Sxy * Syt) * inv;
            float dv = (Sxy * Sxt - Sxx * Syt) * inv;
            int yo = yc - 2;
            if (lane >= 3 && lane <= 60 && x < W) {
                float ou = du, ov = dv;
                if (MODE) { ou += su[i - 2]; ov += sv[i - 2]; }
                FO[yo * W + x] = ou;
                FO[H * W + yo * W + x] = ov;
            }
        }
        dm = d0; d0 = dp;
        sm = s0; s0 = sp;
    }
}

template <int MODE, int H, int W, int TH>
__global__ __launch_bounds__(256, 4) void lk_roll(
    const float* __restrict__ g1, const float* __restrict__ g2,
    const float* __restrict__ fin, float* __restrict__ fout) {
    constexpr int XT = (W + 57) / 58;
    constexpr int TILES = XT * (H / TH);
    const int wid = threadIdx.x >> 6;
    const int b = blockIdx.x % NB;
    const int tix = (blockIdx.x / NB) * 4 + wid;
    if (tix >= TILES) return;
    lk_strip<MODE, H, W, TH>(b, tix, g1, g2, fin, fout);
}

extern "C" void kernel_launch(void* const* d_in, const int* in_sizes, int n_in,
                              void* d_out, int out_size, void* d_ws, size_t ws_size,
                              hipStream_t stream) {
    const float* img1 = (const float*)d_in[0];
    const float* img2 = (const float*)d_in[1];
    float* out = (float*)d_out;
    float* ws = (float*)d_ws;

    constexpr size_t HW0 = 512 * 512, HW1 = 256 * 256, HW2 = 128 * 128, HW3 = 64 * 64;
    constexpr size_t TOT = NB * (HW0 + HW1 + HW2 + HW3);
    float* p1 = ws;
    float* p2 = ws + TOT;
    float* f64 = p2 + TOT;
    float* f128 = f64 + NB * 2 * HW3;
    float* f256 = f128 + NB * 2 * HW2;
    float* p1_0 = p1, * p1_1 = p1 + NB * HW0, * p1_2 = p1_1 + NB * HW1, * p1_3 = p1_2 + NB * HW2;
    float* p2_0 = p2, * p2_1 = p2 + NB * HW0, * p2_2 = p2_1 + NB * HW1, * p2_3 = p2_2 + NB * HW2;

    // gray + full pyramid in one launch (2048 blocks)
    gray_pyr_kernel<<<NB * 256, 256, 0, stream>>>(
        img1, img2, p1_0, p2_0, p1_1, p2_1, p1_2, p2_2, p1_3, p2_3);

    // per-level TH tuned for resident-wave count:
    {
        constexpr int tiles = 2 * 64;    // 64: TH=1
        lk_roll<0, 64, 64, 1><<<NB * ((tiles + 3) / 4), 256, 0, stream>>>(p1_3, p2_3, nullptr, f64);
    }
    {
        constexpr int tiles = 3 * 128;   // 128: TH=1
        lk_roll<1, 128, 128, 1><<<NB * ((tiles + 3) / 4), 256, 0, stream>>>(p1_2, p2_2, f64, f128);
    }
    {
        constexpr int tiles = 5 * 128;   // 256: TH=2
        lk_roll<1, 256, 256, 2><<<NB * ((tiles + 3) / 4), 256, 0, stream>>>(p1_1, p2_1, f128, f256);
    }
    {
        constexpr int tiles = 9 * 128;   // 512: TH=4
        lk_roll<1, 512, 512, 4><<<NB * ((tiles + 3) / 4), 256, 0, stream>>>(p1_0, p2_0, f256, out);
    }
}

// Round 22
// 59.137 us; speedup vs baseline: 1.0125x; 1.0125x over previous
//
#include <hip/hip_runtime.h>

#define NB 8

typedef float f2 __attribute__((ext_vector_type(2)));

// Fused: gray (levels 0,1) + pyramid levels 2,3 via block-local LDS reduction.
__global__ __launch_bounds__(256) void gray_pyr_kernel(
    const float* __restrict__ img1, const float* __restrict__ img2,
    float* __restrict__ g0a, float* __restrict__ g0b,
    float* __restrict__ g1a, float* __restrict__ g1b,
    float* __restrict__ g2a, float* __restrict__ g2b,
    float* __restrict__ g3a, float* __restrict__ g3b) {
    const int W = 512, HW = 512 * 512;
    __shared__ float sL1a[16][17], sL1b[16][17];
    __shared__ float sL2a[8][9], sL2b[8][9];

    int blk = blockIdx.x;
    int b = blk % NB;
    int t = blk / NB;              // 0..255
    int ty = t / 16, tx = t % 16;  // level-1 tile coords
    int lx = threadIdx.x % 16, ly = threadIdx.x / 16;
    int y1 = ty * 16 + ly, x1 = tx * 16 + lx;

    size_t base = (size_t)b * 3 * HW + (size_t)(2 * y1) * W + 2 * x1;
    const float third = 1.0f / 3.0f;

    f2 a0c0 = __builtin_nontemporal_load((const f2*)(img1 + base));
    f2 a1c0 = __builtin_nontemporal_load((const f2*)(img1 + base + W));
    f2 a0c1 = __builtin_nontemporal_load((const f2*)(img1 + base + HW));
    f2 a1c1 = __builtin_nontemporal_load((const f2*)(img1 + base + HW + W));
    f2 a0c2 = __builtin_nontemporal_load((const f2*)(img1 + base + 2 * HW));
    f2 a1c2 = __builtin_nontemporal_load((const f2*)(img1 + base + 2 * HW + W));
    float p00 = (a0c0.x + a0c1.x + a0c2.x) * third;
    float p01 = (a0c0.y + a0c1.y + a0c2.y) * third;
    float p10 = (a1c0.x + a1c1.x + a1c2.x) * third;
    float p11 = (a1c0.y + a1c1.y + a1c2.y) * third;
    size_t gbase = (size_t)b * HW + (size_t)(2 * y1) * W + 2 * x1;
    *(f2*)(g0a + gbase) = (f2){p00, p01};
    *(f2*)(g0a + gbase + W) = (f2){p10, p11};
    float pa = (p00 + p01 + p10 + p11) * 0.25f;
    g1a[(size_t)b * 256 * 256 + y1 * 256 + x1] = pa;
    sL1a[ly][lx] = pa;

    f2 b0c0 = __builtin_nontemporal_load((const f2*)(img2 + base));
    f2 b1c0 = __builtin_nontemporal_load((const f2*)(img2 + base + W));
    f2 b0c1 = __builtin_nontemporal_load((const f2*)(img2 + base + HW));
    f2 b1c1 = __builtin_nontemporal_load((const f2*)(img2 + base + HW + W));
    f2 b0c2 = __builtin_nontemporal_load((const f2*)(img2 + base + 2 * HW));
    f2 b1c2 = __builtin_nontemporal_load((const f2*)(img2 + base + 2 * HW + W));
    float q00 = (b0c0.x + b0c1.x + b0c2.x) * third;
    float q01 = (b0c0.y + b0c1.y + b0c2.y) * third;
    float q10 = (b1c0.x + b1c1.x + b1c2.x) * third;
    float q11 = (b1c0.y + b1c1.y + b1c2.y) * third;
    *(f2*)(g0b + gbase) = (f2){q00, q01};
    *(f2*)(g0b + gbase + W) = (f2){q10, q11};
    float pb = (q00 + q01 + q10 + q11) * 0.25f;
    g1b[(size_t)b * 256 * 256 + y1 * 256 + x1] = pb;
    sL1b[ly][lx] = pb;
    __syncthreads();

    if (threadIdx.x < 64) {
        int y2 = threadIdx.x / 8, x2 = threadIdx.x % 8;
        float va = (sL1a[2 * y2][2 * x2] + sL1a[2 * y2][2 * x2 + 1]
                  + sL1a[2 * y2 + 1][2 * x2] + sL1a[2 * y2 + 1][2 * x2 + 1]) * 0.25f;
        float vb = (sL1b[2 * y2][2 * x2] + sL1b[2 * y2][2 * x2 + 1]
                  + sL1b[2 * y2 + 1][2 * x2] + sL1b[2 * y2 + 1][2 * x2 + 1]) * 0.25f;
        g2a[(size_t)b * 128 * 128 + (ty * 8 + y2) * 128 + tx * 8 + x2] = va;
        g2b[(size_t)b * 128 * 128 + (ty * 8 + y2) * 128 + tx * 8 + x2] = vb;
        sL2a[y2][x2] = va;
        sL2b[y2][x2] = vb;
    }
    __syncthreads();

    if (threadIdx.x < 16) {
        int y3 = threadIdx.x / 4, x3 = threadIdx.x % 4;
        float va = (sL2a[2 * y3][2 * x3] + sL2a[2 * y3][2 * x3 + 1]
                  + sL2a[2 * y3 + 1][2 * x3] + sL2a[2 * y3 + 1][2 * x3 + 1]) * 0.25f;
        float vb = (sL2b[2 * y3][2 * x3] + sL2b[2 * y3][2 * x3 + 1]
                  + sL2b[2 * y3 + 1][2 * x3] + sL2b[2 * y3 + 1][2 * x3 + 1]) * 0.25f;
        g3a[(size_t)b * 64 * 64 + (ty * 4 + y3) * 64 + tx * 4 + x3] = va;
        g3b[(size_t)b * 64 * 64 + (ty * 4 + y3) * 64 + tx * 4 + x3] = vb;
    }
}

// Phase-split rolling strip. MODE=1 warp gather: coalesced G2 row window +
// wave-uniform shuffle bilinear (fast path); pair-load fallback (r19 path).
template <int MODE, int H, int W, int TH>
__device__ __forceinline__ void lk_strip(
    int b, int tix, const float* __restrict__ g1, const float* __restrict__ g2,
    const float* __restrict__ fin, float* __restrict__ fout) {
    constexpr int XT = (W + 57) / 58;
    constexpr int NR = TH + 4;
    constexpr int Hs = H / 2, Ws = W / 2;
    constexpr float scale = (float)(Hs - 1) / (float)(H - 1);

    const int lane = threadIdx.x & 63;
    const int xt = tix % XT, yt = tix / XT;
    const int xb = xt * 58 - 3;
    const int x = xb + lane;
    const bool xin = (x >= 0) && (x < W);

    const float* G1 = g1 + (size_t)b * H * W;
    const float* G2 = g2 + (size_t)b * H * W;
    float* FO = fout + (size_t)b * 2 * H * W;

    const int p0 = yt * TH - 2;

    auto issue1 = [&](int yy) -> float {
        return (xin && yy >= 0 && yy < H) ? G1[yy * W + x] : 0.0f;
    };
    auto dands = [&](float gv, float& d, float& s) {
        float gl = __shfl_up(gv, 1);
        float gr = __shfl_down(gv, 1);
        d = gr - gl;
        s = gl + 2.0f * gv + gr;
    };
    auto hs5 = [&](float v) {
        float a = __shfl_down(v, 1);
        float c = __shfl_down(v, 2);
        float t = v + a + c;
        return __shfl_up(t, 2) + a + c;
    };

    // phase 0: G1 rows (+ G2 row window for MODE=1, coalesced/clamped)
    float g[NR + 2];
#pragma unroll
    for (int j = 0; j < NR + 2; ++j) g[j] = issue1(p0 - 1 + j);

    float g2w[MODE ? NR + 4 : 1];
    if (MODE) {
        int xc = min(max(x, 0), W - 1);
#pragma unroll
        for (int j = 0; j < NR + 4; ++j) {
            int row = min(max(p0 - 2 + j, 0), H - 1);
            g2w[j] = G2[row * W + xc];
        }
    }

    float i2w[NR];
    if (!MODE) {
#pragma unroll
        for (int i = 0; i < NR; ++i) {
            int yc = p0 + i;
            i2w[i] = (xin && yc >= 0 && yc < H) ? G2[yc * W + x] : 0.0f;
        }
    }

    // phase 1: flow walk + warp sample -> i2w
    float su[MODE ? NR : 1], sv[MODE ? NR : 1];
    if (MODE) {
        const float* FU = fin + (size_t)b * 2 * Hs * Ws;
        const float* FV = FU + Hs * Ws;
        float sx = (float)x * scale;
        int cx0 = min(max((int)sx, 0), Ws - 2);
        float wxf = sx - (float)cx0;
        int y0cur = min(max((int)((float)p0 * scale), 0), Hs - 2);
        f2 cu0, cu1, cv0, cv1;
        __builtin_memcpy(&cu0, FU + y0cur * Ws + cx0, 8);
        __builtin_memcpy(&cu1, FU + (y0cur + 1) * Ws + cx0, 8);
        __builtin_memcpy(&cv0, FV + y0cur * Ws + cx0, 8);
        __builtin_memcpy(&cv1, FV + (y0cur + 1) * Ws + cx0, 8);
#pragma unroll
        for (int i = 0; i < NR; ++i) {
            int yc = p0 + i;
            int y0i = min(max((int)((float)yc * scale), 0), Hs - 2);
            if (y0i != y0cur) {  // wave-uniform advance
                cu0 = cu1; cv0 = cv1;
                __builtin_memcpy(&cu1, FU + (y0i + 1) * Ws + cx0, 8);
                __builtin_memcpy(&cv1, FV + (y0i + 1) * Ws + cx0, 8);
                y0cur = y0i;
            }
            float wyf = (float)yc * scale - (float)y0cur;
            float ut = cu0.x + (cu1.x - cu0.x) * wyf;
            float ub = cu0.y + (cu1.y - cu0.y) * wyf;
            float vt = cv0.x + (cv1.x - cv0.x) * wyf;
            float vb = cv0.y + (cv1.y - cv0.y) * wyf;
            su[i] = 2.0f * (ut + (ub - ut) * wxf);
            sv[i] = 2.0f * (vt + (vb - vt) * wxf);

            float xx = (float)x + su[i], yy2 = (float)yc + sv[i];
            float x0f = floorf(xx), y0f = floorf(yy2);
            float wx = xx - x0f, wy = yy2 - y0f;
            int xi = (int)x0f, yi = (int)y0f;
            int dyi = yi - yc;
            int li = xi - xb;
            bool ok = (li >= 0) && (li <= 62) && (xi >= 0) && (xi <= W - 2)
                   && (dyi >= -2) && (dyi <= 1) && (yi >= 0) && (yi <= H - 2);
            int dy0 = __builtin_amdgcn_readfirstlane(dyi);
            bool uni = __all(ok && (dyi == dy0));
            if (uni) {
                // wave-uniform row pair -> 4 shuffles, interior bilinear
                float A, B;
                if (dy0 == -2)      { A = g2w[i];     B = g2w[i + 1]; }
                else if (dy0 == -1) { A = g2w[i + 1]; B = g2w[i + 2]; }
                else if (dy0 == 0)  { A = g2w[i + 2]; B = g2w[i + 3]; }
                else                { A = g2w[i + 3]; B = g2w[i + 4]; }
                float v00 = __shfl(A, li);
                float v01 = __shfl(A, li + 1);
                float v10 = __shfl(B, li);
                float v11 = __shfl(B, li + 1);
                i2w[i] = v00 * ((1.0f - wx) * (1.0f - wy))
                       + v01 * (wx * (1.0f - wy))
                       + v10 * ((1.0f - wx) * wy)
                       + v11 * (wx * wy);
            } else {
                // fallback: r19 pair-load + mask path (bit-exact reference)
                int xl = min(max(xi, 0), W - 2);
                int ya = min(max(yi, 0), H - 1), yb2 = min(max(yi + 1, 0), H - 1);
                f2 wtv, wbv;
                __builtin_memcpy(&wtv, G2 + ya * W + xl, 8);
                __builtin_memcpy(&wbv, G2 + yb2 * W + xl, 8);
                bool t0 = (xi == xl);
                float v00 = t0 ? wtv.x : wtv.y;
                float v01 = t0 ? wtv.y : wtv.x;
                float v10 = t0 ? wbv.x : wbv.y;
                float v11 = t0 ? wbv.y : wbv.x;
                float mx0 = (xi >= 0 && xi < W) ? 1.0f : 0.0f;
                float mx1 = (xi >= -1 && xi < W - 1) ? 1.0f : 0.0f;
                float my0 = (yi >= 0 && yi < H) ? 1.0f : 0.0f;
                float my1 = (yi >= -1 && yi < H - 1) ? 1.0f : 0.0f;
                i2w[i] = v00 * ((1.0f - wx) * (1.0f - wy) * mx0 * my0)
                       + v01 * (wx * (1.0f - wy) * mx1 * my0)
                       + v10 * ((1.0f - wx) * wy * mx0 * my1)
                       + v11 * (wx * wy * mx1 * my1);
            }
        }
    }

    // phase 2: consume
    float hxx[5], hyy[5], hxy[5], hxt[5], hyt[5];
#pragma unroll
    for (int k = 0; k < 5; ++k) { hxx[k] = hyy[k] = hxy[k] = hxt[k] = hyt[k] = 0.0f; }

    float dm, d0, sm, s0, dp, sp;
    dands(g[0], dm, sm);
    dands(g[1], d0, s0);

#pragma unroll
    for (int i = 0; i < NR; ++i) {
        const int yc = p0 + i;
        dands(g[i + 2], dp, sp);
        float Ix = (dm + 2.0f * d0 + dp) * 0.125f;
        float Iy = (sp - sm) * 0.125f;
        float It = i2w[i] - g[i + 1];
        float vm = (xin && yc >= 0 && yc < H) ? 1.0f : 0.0f;
        Ix *= vm; Iy *= vm; It *= vm;

        const int k = i % 5;  // static after full unroll
        hxx[k] = Ix * Ix;
        hyy[k] = Iy * Iy;
        hxy[k] = Ix * Iy;
        hxt[k] = Ix * It;
        hyt[k] = Iy * It;

        if (i >= 4) {
            float vxx = hxx[0] + hxx[1] + hxx[2] + hxx[3] + hxx[4];
            float vyy = hyy[0] + hyy[1] + hyy[2] + hyy[3] + hyy[4];
            float vxy = hxy[0] + hxy[1] + hxy[2] + hxy[3] + hxy[4];
            float vxt = hxt[0] + hxt[1] + hxt[2] + hxt[3] + hxt[4];
            float vyt = hyt[0] + hyt[1] + hyt[2] + hyt[3] + hyt[4];
            float Sxx = hs5(vxx);
            float Syy = hs5(vyy);
            float Sxy = hs5(vxy);
            float Sxt = hs5(vxt);
            float Syt = hs5(vyt);
            float inv = 1.0f / (Sxx * Syy - Sxy * Sxy + 1e-6f);
            float du = (-Syy * Sxt + Sxy * Syt) * inv;
            float dv = (Sxy * Sxt - Sxx * Syt) * inv;
            int yo = yc - 2;
            if (lane >= 3 && lane <= 60 && x < W) {
                float ou = du, ov = dv;
                if (MODE) { ou += su[i - 2]; ov += sv[i - 2]; }
                FO[yo * W + x] = ou;
                FO[H * W + yo * W + x] = ov;
            }
        }
        dm = d0; d0 = dp;
        sm = s0; s0 = sp;
    }
}

template <int MODE, int H, int W, int TH>
__global__ __launch_bounds__(256, 4) void lk_roll(
    const float* __restrict__ g1, const float* __restrict__ g2,
    const float* __restrict__ fin, float* __restrict__ fout) {
    constexpr int XT = (W + 57) / 58;
    constexpr int TILES = XT * (H / TH);
    const int wid = threadIdx.x >> 6;
    const int b = blockIdx.x % NB;
    const int tix = (blockIdx.x / NB) * 4 + wid;
    if (tix >= TILES) return;
    lk_strip<MODE, H, W, TH>(b, tix, g1, g2, fin, fout);
}

extern "C" void kernel_launch(void* const* d_in, const int* in_sizes, int n_in,
                              void* d_out, int out_size, void* d_ws, size_t ws_size,
                              hipStream_t stream) {
    const float* img1 = (const float*)d_in[0];
    const float* img2 = (const float*)d_in[1];
    float* out = (float*)d_out;
    float* ws = (float*)d_ws;

    constexpr size_t HW0 = 512 * 512, HW1 = 256 * 256, HW2 = 128 * 128, HW3 = 64 * 64;
    constexpr size_t TOT = NB * (HW0 + HW1 + HW2 + HW3);
    float* p1 = ws;
    float* p2 = ws + TOT;
    float* f64 = p2 + TOT;
    float* f128 = f64 + NB * 2 * HW3;
    float* f256 = f128 + NB * 2 * HW2;
    float* p1_0 = p1, * p1_1 = p1 + NB * HW0, * p1_2 = p1_1 + NB * HW1, * p1_3 = p1_2 + NB * HW2;
    float* p2_0 = p2, * p2_1 = p2 + NB * HW0, * p2_2 = p2_1 + NB * HW1, * p2_3 = p2_2 + NB * HW2;

    // gray + full pyramid in one launch (2048 blocks)
    gray_pyr_kernel<<<NB * 256, 256, 0, stream>>>(
        img1, img2, p1_0, p2_0, p1_1, p2_1, p1_2, p2_2, p1_3, p2_3);

    // per-level TH tuned for resident-wave count:
    {
        constexpr int tiles = 2 * 64;    // 64: TH=1
        lk_roll<0, 64, 64, 1><<<NB * ((tiles + 3) / 4), 256, 0, stream>>>(p1_3, p2_3, nullptr, f64);
    }
    {
        constexpr int tiles = 3 * 128;   // 128: TH=1
        lk_roll<1, 128, 128, 1><<<NB * ((tiles + 3) / 4), 256, 0, stream>>>(p1_2, p2_2, f64, f128);
    }
    {
        constexpr int tiles = 5 * 128;   // 256: TH=2
        lk_roll<1, 256, 256, 2><<<NB * ((tiles + 3) / 4), 256, 0, stream>>>(p1_1, p2_1, f128, f256);
    }
    {
        constexpr int tiles = 9 * 128;   // 512: TH=4
        lk_roll<1, 512, 512, 4><<<NB * ((tiles + 3) / 4), 256, 0, stream>>>(p1_0, p2_0, f256, out);
    }
}